// Round 1
// baseline (933.866 us; speedup 1.0000x reference)
//
#include <hip/hip_runtime.h>

// VQExpert fused kernel for MI355X (gfx950).
//
// Algebraic collapse:
//   z = x @ Wc.T + bc            where Wc = W_pin@W_down  [32,128], bc = W_pin@b_down + b_pin
//   idx = argmax_c (z . C[c] - 0.5|C[c]|^2)   (== argmin d2, first-min tie-break)
//   y = Y_table[idx]             where Y_table[c] = clip((C[c]@W_pout.T+b_pout)@W_up.T+b_up, -1, 1)
//
// d_out layout (all float32): y [N*128] | indices-as-float [N] | commit_loss [1]

#define CODE_D 32
#define NUM_C  256
#define KCH    32
#define LSTR   36   // LDS row stride in floats (32 + 4 pad) = 144 B, 16B-aligned

// ---------------- prep kernels (rebuilt every launch; ws is re-poisoned) ------------

__global__ void vq_prep1(const float* __restrict__ Wd, const float* __restrict__ bd,
                         const float* __restrict__ Wp, const float* __restrict__ bp,
                         const float* __restrict__ cb,
                         float* __restrict__ Wc, float* __restrict__ bc,
                         float* __restrict__ cbias) {
    const int t = threadIdx.x;   // 256 threads, 1 block
    // Wc[j][k] = sum_m Wp[j][m] * Wd[m][k]   (double accum for fidelity)
    for (int e = t; e < 32 * 128; e += 256) {
        const int j = e >> 7, k = e & 127;
        double s = 0.0;
        for (int m = 0; m < 128; ++m)
            s += (double)Wp[j * 128 + m] * (double)Wd[m * 128 + k];
        Wc[e] = (float)s;
    }
    if (t < 32) {
        double s = (double)bp[t];
        for (int m = 0; m < 128; ++m) s += (double)Wp[t * 128 + m] * (double)bd[m];
        bc[t] = (float)s;
    }
    // cbias[c] = -0.5 * |C[c]|^2
    {
        float s = 0.f;
        for (int d = 0; d < CODE_D; ++d) { float v = cb[t * CODE_D + d]; s += v * v; }
        cbias[t] = -0.5f * s;
    }
}

__global__ void vq_prep2(const float* __restrict__ cb, const float* __restrict__ Wpo,
                         const float* __restrict__ bpo, const float* __restrict__ Wu,
                         const float* __restrict__ bu, float* __restrict__ ytab) {
    __shared__ float v[128];
    const int c = blockIdx.x;    // 256 blocks
    const int t = threadIdx.x;   // 128 threads
    // v[m] = b_pout[m] + sum_d C[c][d] * W_pout[m][d]
    float s = bpo[t];
    for (int d = 0; d < CODE_D; ++d) s += cb[c * CODE_D + d] * Wpo[t * CODE_D + d];
    v[t] = s;
    __syncthreads();
    // y[k] = clip(b_up[k] + sum_m v[m] * W_up[k][m], -1, 1)
    float o = bu[t];
    for (int m = 0; m < 128; ++m) o += v[m] * Wu[t * 128 + m];
    o = fminf(fmaxf(o, -1.0f), 1.0f);
    ytab[c * 128 + t] = o;
}

// ---------------- main fused kernel ------------------------------------------------

__global__ __launch_bounds__(256, 4) void vq_main(
    const float* __restrict__ x,      // [N,128]
    const float* __restrict__ Wc,     // [32,128]
    const float* __restrict__ bc,     // [32]
    const float* __restrict__ cb,     // codebook [256,32]
    const float* __restrict__ cbias,  // [256]
    const float* __restrict__ ytab,   // [256,128]
    float* __restrict__ y,            // [N,128]
    float* __restrict__ idx_out,      // [N] (written as float values)
    float* __restrict__ loss_out,     // [1]
    int N) {
    __shared__ float lds[256 * LSTR];   // 36 KB x-tile chunk, padded stride
    __shared__ int sidx[256];

    const int t = threadIdx.x;
    const int row0 = blockIdx.x * 256;
    const int myrow = row0 + t;

    float z[CODE_D];
#pragma unroll
    for (int j = 0; j < CODE_D; ++j) z[j] = bc[j];

    // ---- z = x @ Wc.T + bc, K-chunked through LDS ----
    const int rr = t >> 3;  // 0..31 : staging row group
    const int qq = t & 7;   // 0..7  : staging quad within row
    for (int kc = 0; kc < 128; kc += KCH) {
        // stage 256 rows x 32 cols: coalesced float4 global loads -> padded LDS
#pragma unroll
        for (int i = 0; i < 8; ++i) {
            const int r = i * 32 + rr;
            const int grow = row0 + r;
            float4 v = make_float4(0.f, 0.f, 0.f, 0.f);
            if (grow < N)
                v = *reinterpret_cast<const float4*>(x + (size_t)grow * 128 + kc + qq * 4);
            *reinterpret_cast<float4*>(&lds[r * LSTR + qq * 4]) = v;
        }
        __syncthreads();
        // each thread consumes its own row's chunk; Wc is block-uniform -> s_load
#pragma unroll
        for (int q = 0; q < KCH / 4; ++q) {
            const float4 xv = *reinterpret_cast<const float4*>(&lds[t * LSTR + q * 4]);
            const int kb = kc + q * 4;
#pragma unroll
            for (int j = 0; j < CODE_D; ++j) {
                const float* w = Wc + j * 128 + kb;
                z[j] += w[0] * xv.x + w[1] * xv.y + w[2] * xv.z + w[3] * xv.w;
            }
        }
        __syncthreads();
    }

    // ---- scores: argmax_c (z . C[c] + cbias[c]) == argmin d2 (first-index ties) ----
    float best = -3.0e38f;
    int besti = 0;
#pragma unroll 4
    for (int c = 0; c < NUM_C; ++c) {
        const float* crow = cb + c * CODE_D;
        float s0 = 0.f, s1 = 0.f, s2 = 0.f, s3 = 0.f;
#pragma unroll
        for (int d = 0; d < CODE_D; d += 4) {
            s0 += crow[d + 0] * z[d + 0];
            s1 += crow[d + 1] * z[d + 1];
            s2 += crow[d + 2] * z[d + 2];
            s3 += crow[d + 3] * z[d + 3];
        }
        const float s = ((s0 + s1) + (s2 + s3)) + cbias[c];
        if (s > best) { best = s; besti = c; }
    }

    sidx[t] = besti;
    if (myrow < N) idx_out[myrow] = (float)besti;
    __syncthreads();

    // ---- cooperative coalesced table-gather store of y ----
    const int rsub = t >> 5;  // 0..7
    const int c4 = t & 31;    // float4 column
#pragma unroll
    for (int i = 0; i < 32; ++i) {
        const int r = i * 8 + rsub;
        const int grow = row0 + r;
        if (grow < N) {
            const int ci = sidx[r];
            const float4 v = *reinterpret_cast<const float4*>(ytab + ci * 128 + c4 * 4);
            *reinterpret_cast<float4*>(y + (size_t)grow * 128 + c4 * 4) = v;
        }
    }

    if (blockIdx.x == 0 && t == 0) loss_out[0] = 0.0f;
}

// ---------------- launch -----------------------------------------------------------

extern "C" void kernel_launch(void* const* d_in, const int* in_sizes, int n_in,
                              void* d_out, int out_size, void* d_ws, size_t ws_size,
                              hipStream_t stream) {
    const float* x   = (const float*)d_in[0];
    const float* Wd  = (const float*)d_in[1];
    const float* bd  = (const float*)d_in[2];
    const float* Wp  = (const float*)d_in[3];
    const float* bp  = (const float*)d_in[4];
    const float* cb  = (const float*)d_in[5];
    const float* Wpo = (const float*)d_in[6];
    const float* bpo = (const float*)d_in[7];
    const float* Wu  = (const float*)d_in[8];
    const float* bu  = (const float*)d_in[9];

    const int N = in_sizes[0] / 128;

    // ws layout (floats): Wc[4096] | bc[32] | cbias[256] | ytab[32768]
    float* ws    = (float*)d_ws;
    float* Wc    = ws;
    float* bc    = ws + 4096;
    float* cbias = ws + 4128;
    float* ytab  = ws + 4384;

    float* y    = (float*)d_out;
    float* idxf = y + (size_t)N * 128;
    float* loss = idxf + N;

    vq_prep1<<<1, 256, 0, stream>>>(Wd, bd, Wp, bp, cb, Wc, bc, cbias);
    vq_prep2<<<NUM_C, 128, 0, stream>>>(cb, Wpo, bpo, Wu, bu, ytab);

    const int blocks = (N + 255) / 256;
    vq_main<<<blocks, 256, 0, stream>>>(x, Wc, bc, cb, cbias, ytab, y, idxf, loss, N);
}